// Round 1
// baseline (335.808 us; speedup 1.0000x reference)
//
#include <hip/hip_runtime.h>

constexpr int LMAX = 8;
constexpr int NCOL = (LMAX + 1) * (LMAX + 1);   // 81
constexpr int PTS  = 64;                         // points per block (one wave)
constexpr int TILE_FLOATS = PTS * NCOL;          // 5184
constexpr int VEC4_ITERS  = TILE_FLOATS / 4 / PTS; // 20 (covers 5120 floats)

__device__ __forceinline__ void emit_col(float* row, const float* __restrict__ F,
                                         int l, int m, float Q, float sm, float cm) {
    const int fbase = l * (l + 1) / 2;
    const int cbase = l * l + l;
    if (m == 0) {
        const float inv_sqrt2 = 0.70710678118654752440f;
        row[cbase] = F[fbase] * Q * inv_sqrt2;
    } else {
        float t = F[fbase + m] * Q;
        row[cbase - m] = t * sm;
        row[cbase + m] = t * cm;
    }
}

__global__ __launch_bounds__(PTS) void sh_kernel(const float* __restrict__ xyz,
                                                 const float* __restrict__ F,
                                                 float* __restrict__ out, int n) {
    __shared__ float tile[TILE_FLOATS];   // 20736 B
    const int lane    = threadIdx.x;
    const int base_pt = blockIdx.x * PTS;
    const int i       = base_pt + lane;

    float x = 0.0f, y = 0.0f, z = 1.0f;
    if (i < n) {
        x = xyz[3 * i + 0];
        y = xyz[3 * i + 1];
        z = xyz[3 * i + 2];
    }
    const float rsq  = x * x + y * y + z * z;
    const float rinv = rsqrtf(rsq);
    x *= rinv; y *= rinv; z *= rinv;

    float* row = &tile[lane * NCOL];

    float Qmm = 1.0f;           // Q[m,m]
    float sm = 0.0f, cm = 1.0f; // s[m], c[m]

#pragma unroll
    for (int m = 0; m <= LMAX; ++m) {
        if (m > 0) {
            Qmm = -(float)(2 * m - 1) * Qmm;
            const float s_new = x * sm + y * cm;
            const float c_new = x * cm - y * sm;
            sm = s_new; cm = c_new;
        }
        // l = m
        float Qp = Qmm;
        emit_col(row, F, m, m, Qp, sm, cm);
        if (m < LMAX) {
            // l = m+1 : Q[m+1,m] = (2m+1) * z * Q[m,m]
            float Qc = (float)(2 * m + 1) * z * Qmm;
            emit_col(row, F, m + 1, m, Qc, sm, cm);
#pragma unroll
            for (int l = m + 2; l <= LMAX; ++l) {
                const float Qn = ((float)(2 * l - 1) * z * Qc
                                  - (float)(l + m - 1) * Qp) * (1.0f / (float)(l - m));
                Qp = Qc; Qc = Qn;
                emit_col(row, F, l, m, Qc, sm, cm);
            }
        }
    }

    __syncthreads();

    const long long tile_base = (long long)base_pt * NCOL;   // float index into out
    if (base_pt + PTS <= n) {
        // fully coalesced: region of 5184 floats (16B-aligned: 20736*blockIdx)
        const float4* src = (const float4*)tile;
        float4* dst = (float4*)(out + tile_base);
#pragma unroll
        for (int k = 0; k < VEC4_ITERS; ++k) {
            dst[k * PTS + lane] = src[k * PTS + lane];
        }
        // remaining 64 floats
        out[tile_base + VEC4_ITERS * PTS * 4 + lane] = tile[VEC4_ITERS * PTS * 4 + lane];
    } else {
        const long long lim = (long long)n * NCOL;
        for (int k = lane; k < TILE_FLOATS; k += PTS) {
            const long long gi = tile_base + k;
            if (gi < lim) out[gi] = tile[k];
        }
    }
}

extern "C" void kernel_launch(void* const* d_in, const int* in_sizes, int n_in,
                              void* d_out, int out_size, void* d_ws, size_t ws_size,
                              hipStream_t stream) {
    const float* xyz = (const float*)d_in[0];
    const float* F   = (const float*)d_in[1];
    float* out       = (float*)d_out;
    const int n      = in_sizes[0] / 3;
    const int grid   = (n + PTS - 1) / PTS;
    sh_kernel<<<grid, PTS, 0, stream>>>(xyz, F, out, n);
}